// Round 2
// baseline (2819.117 us; speedup 1.0000x reference)
//
#include <hip/hip_runtime.h>

#define NN   100000
#define EE   1600000
constexpr int RR = 8;
constexpr int BBASES = 4;
constexpr int SCAN_CHUNK = 1024;
constexpr int NBLK = (NN + SCAN_CHUNK - 1) / SCAN_CHUNK; // 98

__device__ __forceinline__ unsigned pack2(float x, float y) {
    unsigned xu = __float_as_uint(x);
    unsigned yu = __float_as_uint(y);
    xu = (xu + 0x7fffu + ((xu >> 16) & 1u)) >> 16;
    yu = (yu + 0x7fffu + ((yu >> 16) & 1u)) & 0xffff0000u;
    return xu | yu;
}

// ---------------- CSR build ----------------

__global__ __launch_bounds__(256) void count_kernel(const int* __restrict__ dst,
                                                    int* __restrict__ counts) {
    int e = blockIdx.x * 256 + threadIdx.x;
    if (e < EE) atomicAdd(&counts[dst[e]], 1);
}

__global__ __launch_bounds__(256) void scan1(const int* __restrict__ counts,
                                             int* __restrict__ offsets,
                                             int* __restrict__ totals) {
    __shared__ int lds[256];
    int b = blockIdx.x, tid = threadIdx.x;
    int base = b * SCAN_CHUNK + tid * 4;
    int v0 = (base + 0 < NN) ? counts[base + 0] : 0;
    int v1 = (base + 1 < NN) ? counts[base + 1] : 0;
    int v2 = (base + 2 < NN) ? counts[base + 2] : 0;
    int v3 = (base + 3 < NN) ? counts[base + 3] : 0;
    int s0 = v0, s1 = s0 + v1, s2 = s1 + v2, s3 = s2 + v3;
    lds[tid] = s3;
    __syncthreads();
    for (int d = 1; d < 256; d <<= 1) {
        int x = (tid >= d) ? lds[tid - d] : 0;
        __syncthreads();
        lds[tid] += x;
        __syncthreads();
    }
    int incl = lds[tid];
    int prefix = incl - s3;
    if (base + 0 < NN) offsets[base + 0] = prefix;
    if (base + 1 < NN) offsets[base + 1] = prefix + s0;
    if (base + 2 < NN) offsets[base + 2] = prefix + s1;
    if (base + 3 < NN) offsets[base + 3] = prefix + s2;
    if (tid == 255) totals[b] = lds[255];
}

__global__ void scan2(int* __restrict__ totals, int* __restrict__ offsets) {
    int run = 0;
    for (int b = 0; b < NBLK; ++b) { int x = totals[b]; totals[b] = run; run += x; }
    offsets[NN] = run;
}

__global__ __launch_bounds__(256) void scan3(int* __restrict__ offsets,
                                             const int* __restrict__ totals) {
    int i = blockIdx.x * 256 + threadIdx.x;
    if (i < NN) offsets[i] += totals[i >> 10];
}

__global__ __launch_bounds__(256) void fill_kernel(const int* __restrict__ src,
                                                   const int* __restrict__ dst,
                                                   const int* __restrict__ et,
                                                   const int* __restrict__ offsets,
                                                   int* __restrict__ cursor,
                                                   int* __restrict__ packed) {
    int e = blockIdx.x * 256 + threadIdx.x;
    if (e < EE) {
        int d = dst[e];
        int p = offsets[d] + atomicAdd(&cursor[d], 1);
        packed[p] = src[e] | (et[e] << 20);
    }
}

// ---------------- input layer: hout = relu(feat @ win + bias), bf16 out ----------------

__global__ __launch_bounds__(256) void in_gemm(const float* __restrict__ feat,   // [N][128]
                                               const float* __restrict__ win,    // [128][128]
                                               const float* __restrict__ bias,   // [128]
                                               unsigned* __restrict__ hout) {    // [N][64] bf16x2
    __shared__ unsigned short A_lds[64][136];
    __shared__ float Bs[2][32][128];
    int tid = threadIdx.x;
    int nbase = blockIdx.x * 64;

    // stage A tile (f32 -> bf16), along-K layout, 16B-aligned rows
#pragma unroll
    for (int q = 0; q < 8; ++q) {
        int lin = q * 256 + tid;
        int row = lin >> 5, c4 = (lin & 31) * 4;
        int grow = nbase + row;
        float4 v = make_float4(0.f, 0.f, 0.f, 0.f);
        if (grow < NN) v = *(const float4*)(feat + (size_t)grow * 128 + c4);
        unsigned* d = (unsigned*)&A_lds[row][c4];
        d[0] = pack2(v.x, v.y);
        d[1] = pack2(v.z, v.w);
    }
    int tc = tid & 31, tr = tid >> 5;
    float acc[8][4] = {};
    float4 breg[4];
    // prologue: stage chunk 0
#pragma unroll
    for (int q = 0; q < 4; ++q) {
        int lin = q * 256 + tid;
        breg[q] = *(const float4*)(win + (size_t)(lin >> 5) * 128 + (lin & 31) * 4);
    }
#pragma unroll
    for (int q = 0; q < 4; ++q) {
        int lin = q * 256 + tid;
        *(float4*)&Bs[0][lin >> 5][(lin & 31) * 4] = breg[q];
    }
    for (int c = 0; c < 4; ++c) {
        __syncthreads();
        if (c < 3) {
            const float* bsrc = win + (size_t)(c + 1) * 32 * 128;
#pragma unroll
            for (int q = 0; q < 4; ++q) {
                int lin = q * 256 + tid;
                breg[q] = *(const float4*)(bsrc + (size_t)(lin >> 5) * 128 + (lin & 31) * 4);
            }
        }
        int kloc = c * 32;
        const float(*Bcur)[128] = Bs[c & 1];
#pragma unroll
        for (int k8 = 0; k8 < 4; ++k8) {
            uint4 araw[8];
#pragma unroll
            for (int i = 0; i < 8; ++i)
                araw[i] = *(const uint4*)&A_lds[tr * 8 + i][kloc + k8 * 8];
#pragma unroll
            for (int kk = 0; kk < 8; ++kk) {
                float4 bv = *(const float4*)&Bcur[k8 * 8 + kk][tc * 4];
#pragma unroll
                for (int i = 0; i < 8; ++i) {
                    unsigned dw = ((const unsigned*)&araw[i])[kk >> 1];
                    float av = __uint_as_float((kk & 1) ? (dw & 0xffff0000u) : (dw << 16));
                    acc[i][0] = fmaf(av, bv.x, acc[i][0]);
                    acc[i][1] = fmaf(av, bv.y, acc[i][1]);
                    acc[i][2] = fmaf(av, bv.z, acc[i][2]);
                    acc[i][3] = fmaf(av, bv.w, acc[i][3]);
                }
            }
        }
        __syncthreads();
        if (c < 3) {
#pragma unroll
            for (int q = 0; q < 4; ++q) {
                int lin = q * 256 + tid;
                *(float4*)&Bs[(c + 1) & 1][lin >> 5][(lin & 31) * 4] = breg[q];
            }
        }
    }
    float4 bb = *(const float4*)(bias + tc * 4);
#pragma unroll
    for (int i = 0; i < 8; ++i) {
        int row = nbase + tr * 8 + i;
        if (row < NN) {
            float o0 = fmaxf(acc[i][0] + bb.x, 0.f);
            float o1 = fmaxf(acc[i][1] + bb.y, 0.f);
            float o2 = fmaxf(acc[i][2] + bb.z, 0.f);
            float o3 = fmaxf(acc[i][3] + bb.w, 0.f);
            hout[(size_t)row * 64 + tc * 2]     = pack2(o0, o1);
            hout[(size_t)row * 64 + tc * 2 + 1] = pack2(o2, o3);
        }
    }
}

// ---------------- fused RelGraphConv layer ----------------
// Phase 1: per-wave edge aggregation, wcomp-weighted, t-tile (bf16) + h-tile in LDS.
// Phase 2: h_out = relu([t | h] @ [basisflat ; loopw] + hbias), bf16 out.

__global__ __launch_bounds__(256) void conv_fused(const unsigned* __restrict__ hin,  // [N][64] bf16x2
                                                  const int* __restrict__ offsets,
                                                  const int* __restrict__ packed,
                                                  const float* __restrict__ wcomp,      // [8][4]
                                                  const float* __restrict__ basisflat,  // [512][128]
                                                  const float* __restrict__ loopw,      // [128][128]
                                                  const float* __restrict__ hbias,      // [128]
                                                  unsigned* __restrict__ hout) {        // [N][64]
    __shared__ unsigned short t_lds[64][528];  // [node][k] bf16, rows 1056B (16B-mult)
    __shared__ unsigned short h_lds[64][136];  // [node][k] bf16
    __shared__ float Bs[2][32][128];
    __shared__ float wc[32];

    int tid = threadIdx.x;
    int wave = tid >> 6, lane = tid & 63;
    int nbase = blockIdx.x * 64;

    if (tid < 32) wc[tid] = wcomp[tid];
    __syncthreads();

    // ---- phase 1: aggregation (each wave owns 16 nodes) ----
    for (int j = 0; j < 16; ++j) {
        int nl = wave * 16 + j;
        int n = nbase + nl;
        float t0x = 0.f, t0y = 0.f, t1x = 0.f, t1y = 0.f;
        float t2x = 0.f, t2y = 0.f, t3x = 0.f, t3y = 0.f;
        unsigned hself = 0u;
        if (n < NN) {
            hself = hin[(size_t)n * 64 + lane];
            int beg = offsets[n], end = offsets[n + 1];
            for (int e = beg; e < end; ++e) {
                unsigned u = (unsigned)packed[e];
                int srcn = u & 0xFFFFF;
                int r = (int)(u >> 20);
                unsigned hv = hin[(size_t)srcn * 64 + lane];
                float hx = __uint_as_float(hv << 16);
                float hy = __uint_as_float(hv & 0xffff0000u);
                float w0 = wc[r * 4 + 0], w1 = wc[r * 4 + 1];
                float w2 = wc[r * 4 + 2], w3 = wc[r * 4 + 3];
                t0x = fmaf(w0, hx, t0x); t0y = fmaf(w0, hy, t0y);
                t1x = fmaf(w1, hx, t1x); t1y = fmaf(w1, hy, t1y);
                t2x = fmaf(w2, hx, t2x); t2y = fmaf(w2, hy, t2y);
                t3x = fmaf(w3, hx, t3x); t3y = fmaf(w3, hy, t3y);
            }
        }
        *(unsigned*)&t_lds[nl][0 * 128 + 2 * lane] = pack2(t0x, t0y);
        *(unsigned*)&t_lds[nl][1 * 128 + 2 * lane] = pack2(t1x, t1y);
        *(unsigned*)&t_lds[nl][2 * 128 + 2 * lane] = pack2(t2x, t2y);
        *(unsigned*)&t_lds[nl][3 * 128 + 2 * lane] = pack2(t3x, t3y);
        *(unsigned*)&h_lds[nl][2 * lane] = hself;
    }
    __syncthreads();

    // ---- phase 2: GEMM K = 512 (t x basis) + 128 (h x loopw) ----
    int tc = tid & 31, tr = tid >> 5;
    float acc[8][4] = {};
    float4 breg[4];
#pragma unroll
    for (int q = 0; q < 4; ++q) {
        int lin = q * 256 + tid;
        breg[q] = *(const float4*)(basisflat + (size_t)(lin >> 5) * 128 + (lin & 31) * 4);
    }
#pragma unroll
    for (int q = 0; q < 4; ++q) {
        int lin = q * 256 + tid;
        *(float4*)&Bs[0][lin >> 5][(lin & 31) * 4] = breg[q];
    }
    for (int c = 0; c < 20; ++c) {
        __syncthreads();
        if (c < 19) {
            int cn = c + 1;
            const float* bsrc = (cn < 16) ? basisflat + (size_t)cn * 32 * 128
                                          : loopw + (size_t)(cn - 16) * 32 * 128;
#pragma unroll
            for (int q = 0; q < 4; ++q) {
                int lin = q * 256 + tid;
                breg[q] = *(const float4*)(bsrc + (size_t)(lin >> 5) * 128 + (lin & 31) * 4);
            }
        }
        const unsigned short* Abase;
        int Astride, kloc;
        if (c < 16) { Abase = &t_lds[0][0]; Astride = 528; kloc = c * 32; }
        else        { Abase = &h_lds[0][0]; Astride = 136; kloc = (c - 16) * 32; }
        const float(*Bcur)[128] = Bs[c & 1];
#pragma unroll
        for (int k8 = 0; k8 < 4; ++k8) {
            uint4 araw[8];
#pragma unroll
            for (int i = 0; i < 8; ++i)
                araw[i] = *(const uint4*)(Abase + (size_t)(tr * 8 + i) * Astride + kloc + k8 * 8);
#pragma unroll
            for (int kk = 0; kk < 8; ++kk) {
                float4 bv = *(const float4*)&Bcur[k8 * 8 + kk][tc * 4];
#pragma unroll
                for (int i = 0; i < 8; ++i) {
                    unsigned dw = ((const unsigned*)&araw[i])[kk >> 1];
                    float av = __uint_as_float((kk & 1) ? (dw & 0xffff0000u) : (dw << 16));
                    acc[i][0] = fmaf(av, bv.x, acc[i][0]);
                    acc[i][1] = fmaf(av, bv.y, acc[i][1]);
                    acc[i][2] = fmaf(av, bv.z, acc[i][2]);
                    acc[i][3] = fmaf(av, bv.w, acc[i][3]);
                }
            }
        }
        __syncthreads();
        if (c < 19) {
#pragma unroll
            for (int q = 0; q < 4; ++q) {
                int lin = q * 256 + tid;
                *(float4*)&Bs[(c + 1) & 1][lin >> 5][(lin & 31) * 4] = breg[q];
            }
        }
    }
    float4 bb = *(const float4*)(hbias + tc * 4);
#pragma unroll
    for (int i = 0; i < 8; ++i) {
        int row = nbase + tr * 8 + i;
        if (row < NN) {
            float o0 = fmaxf(acc[i][0] + bb.x, 0.f);
            float o1 = fmaxf(acc[i][1] + bb.y, 0.f);
            float o2 = fmaxf(acc[i][2] + bb.z, 0.f);
            float o3 = fmaxf(acc[i][3] + bb.w, 0.f);
            hout[(size_t)row * 64 + tc * 2]     = pack2(o0, o1);
            hout[(size_t)row * 64 + tc * 2 + 1] = pack2(o2, o3);
        }
    }
}

// ---------------- output layer: out = relu(h @ wout + bout), f32 out ----------------

__global__ __launch_bounds__(256) void out_gemm(const unsigned* __restrict__ hin,  // [N][64] bf16x2
                                                const float* __restrict__ wout,    // [128][64]
                                                const float* __restrict__ bout,    // [64]
                                                float* __restrict__ outp) {        // [N][64]
    __shared__ unsigned short A_lds[64][136];
    __shared__ float Bs[2][32][64];
    int tid = threadIdx.x;
    int nbase = blockIdx.x * 64;
#pragma unroll
    for (int q = 0; q < 16; ++q) {
        int lin = q * 256 + tid;
        int row = lin >> 6, cu = lin & 63;
        unsigned v = 0u;
        if (nbase + row < NN) v = hin[(size_t)(nbase + row) * 64 + cu];
        *(unsigned*)&A_lds[row][cu * 2] = v;
    }
    int tc = tid & 15, tr = tid >> 4;  // cols tc*4 (64), rows tr*4 (64)
    float acc[4][4] = {};
    float4 breg[2];
#pragma unroll
    for (int q = 0; q < 2; ++q) {
        int lin = q * 256 + tid;
        breg[q] = *(const float4*)(wout + (size_t)(lin >> 4) * 64 + (lin & 15) * 4);
    }
#pragma unroll
    for (int q = 0; q < 2; ++q) {
        int lin = q * 256 + tid;
        *(float4*)&Bs[0][lin >> 4][(lin & 15) * 4] = breg[q];
    }
    for (int c = 0; c < 4; ++c) {
        __syncthreads();
        if (c < 3) {
            const float* bsrc = wout + (size_t)(c + 1) * 32 * 64;
#pragma unroll
            for (int q = 0; q < 2; ++q) {
                int lin = q * 256 + tid;
                breg[q] = *(const float4*)(bsrc + (size_t)(lin >> 4) * 64 + (lin & 15) * 4);
            }
        }
        int kloc = c * 32;
        const float(*Bcur)[64] = Bs[c & 1];
#pragma unroll
        for (int k8 = 0; k8 < 4; ++k8) {
            uint4 araw[4];
#pragma unroll
            for (int i = 0; i < 4; ++i)
                araw[i] = *(const uint4*)&A_lds[tr * 4 + i][kloc + k8 * 8];
#pragma unroll
            for (int kk = 0; kk < 8; ++kk) {
                float4 bv = *(const float4*)&Bcur[k8 * 8 + kk][tc * 4];
#pragma unroll
                for (int i = 0; i < 4; ++i) {
                    unsigned dw = ((const unsigned*)&araw[i])[kk >> 1];
                    float av = __uint_as_float((kk & 1) ? (dw & 0xffff0000u) : (dw << 16));
                    acc[i][0] = fmaf(av, bv.x, acc[i][0]);
                    acc[i][1] = fmaf(av, bv.y, acc[i][1]);
                    acc[i][2] = fmaf(av, bv.z, acc[i][2]);
                    acc[i][3] = fmaf(av, bv.w, acc[i][3]);
                }
            }
        }
        __syncthreads();
        if (c < 3) {
#pragma unroll
            for (int q = 0; q < 2; ++q) {
                int lin = q * 256 + tid;
                *(float4*)&Bs[(c + 1) & 1][lin >> 4][(lin & 15) * 4] = breg[q];
            }
        }
    }
    float4 bb = *(const float4*)(bout + tc * 4);
#pragma unroll
    for (int i = 0; i < 4; ++i) {
        int row = nbase + tr * 4 + i;
        if (row < NN) {
            float4 o;
            o.x = fmaxf(acc[i][0] + bb.x, 0.f);
            o.y = fmaxf(acc[i][1] + bb.y, 0.f);
            o.z = fmaxf(acc[i][2] + bb.z, 0.f);
            o.w = fmaxf(acc[i][3] + bb.w, 0.f);
            *(float4*)(outp + (size_t)row * 64 + tc * 4) = o;
        }
    }
}

// ---------------- launch ----------------

static inline size_t align256(size_t x) { return (x + 255) & ~(size_t)255; }

extern "C" void kernel_launch(void* const* d_in, const int* in_sizes, int n_in,
                              void* d_out, int out_size, void* d_ws, size_t ws_size,
                              hipStream_t stream) {
    const float* feat   = (const float*)d_in[0];
    const float* win    = (const float*)d_in[1];
    const float* bin_   = (const float*)d_in[2];
    const float* basis0 = (const float*)d_in[3];
    const float* wcomp0 = (const float*)d_in[4];
    const float* loop0  = (const float*)d_in[5];
    const float* hbias0 = (const float*)d_in[6];
    const float* basis1 = (const float*)d_in[7];
    const float* wcomp1 = (const float*)d_in[8];
    const float* loop1  = (const float*)d_in[9];
    const float* hbias1 = (const float*)d_in[10];
    const float* wout   = (const float*)d_in[11];
    const float* bout   = (const float*)d_in[12];
    const int*   src    = (const int*)d_in[13];
    const int*   dst    = (const int*)d_in[14];
    const int*   etyp   = (const int*)d_in[15];
    float* outp = (float*)d_out;

    char* w = (char*)d_ws;
    unsigned* hA = (unsigned*)w; w += align256((size_t)NN * 64 * 4);   // 25.6 MB (bf16x2)
    unsigned* hB = (unsigned*)w; w += align256((size_t)NN * 64 * 4);   // 25.6 MB
    int* offsets = (int*)w;      w += align256((size_t)(NN + 1) * 4);
    int* counts  = (int*)w;      w += align256((size_t)NN * 4);
    int* cursor  = (int*)w;      w += align256((size_t)NN * 4);
    int* totals  = (int*)w;      w += align256((size_t)NBLK * 4);
    int* packed  = (int*)w;      w += align256((size_t)EE * 4);        // 6.4 MB

    hipMemsetAsync(counts, 0, (size_t)NN * 4, stream);
    hipMemsetAsync(cursor, 0, (size_t)NN * 4, stream);
    count_kernel<<<(EE + 255) / 256, 256, 0, stream>>>(dst, counts);
    scan1<<<NBLK, 256, 0, stream>>>(counts, offsets, totals);
    scan2<<<1, 1, 0, stream>>>(totals, offsets);
    scan3<<<(NN + 255) / 256, 256, 0, stream>>>(offsets, totals);
    fill_kernel<<<(EE + 255) / 256, 256, 0, stream>>>(src, dst, etyp, offsets, cursor, packed);

    int nblocks = (NN + 63) / 64;  // 1563
    in_gemm<<<nblocks, 256, 0, stream>>>(feat, win, bin_, hA);
    conv_fused<<<nblocks, 256, 0, stream>>>(hA, offsets, packed, wcomp0, basis0, loop0, hbias0, hB);
    conv_fused<<<nblocks, 256, 0, stream>>>(hB, offsets, packed, wcomp1, basis1, loop1, hbias1, hA);
    out_gemm<<<nblocks, 256, 0, stream>>>(hA, wout, bout, outp);
}

// Round 3
// 655.169 us; speedup vs baseline: 4.3029x; 4.3029x over previous
//
#include <hip/hip_runtime.h>

#define NN   100000
#define EE   1600000
constexpr int RR = 8;
constexpr int BBASES = 4;
constexpr int SCAN_CHUNK = 1024;
constexpr int NBLK = (NN + SCAN_CHUNK - 1) / SCAN_CHUNK; // 98

typedef __attribute__((ext_vector_type(8))) short short8;
typedef __attribute__((ext_vector_type(4))) float f32x4;

__device__ __forceinline__ unsigned pack2(float x, float y) {
    unsigned xu = __float_as_uint(x);
    unsigned yu = __float_as_uint(y);
    xu = (xu + 0x7fffu + ((xu >> 16) & 1u)) >> 16;
    yu = (yu + 0x7fffu + ((yu >> 16) & 1u)) & 0xffff0000u;
    return xu | yu;
}

__device__ __forceinline__ unsigned short bf16r(float x) {
    unsigned u = __float_as_uint(x);
    return (unsigned short)((u + 0x7fffu + ((u >> 16) & 1u)) >> 16);
}

// ---------------- CSR build ----------------

__global__ __launch_bounds__(256) void count_kernel(const int* __restrict__ dst,
                                                    int* __restrict__ counts) {
    int e = blockIdx.x * 256 + threadIdx.x;
    if (e < EE) atomicAdd(&counts[dst[e]], 1);
}

__global__ __launch_bounds__(256) void scan1(const int* __restrict__ counts,
                                             int* __restrict__ offsets,
                                             int* __restrict__ totals) {
    __shared__ int lds[256];
    int b = blockIdx.x, tid = threadIdx.x;
    int base = b * SCAN_CHUNK + tid * 4;
    int v0 = (base + 0 < NN) ? counts[base + 0] : 0;
    int v1 = (base + 1 < NN) ? counts[base + 1] : 0;
    int v2 = (base + 2 < NN) ? counts[base + 2] : 0;
    int v3 = (base + 3 < NN) ? counts[base + 3] : 0;
    int s0 = v0, s1 = s0 + v1, s2 = s1 + v2, s3 = s2 + v3;
    lds[tid] = s3;
    __syncthreads();
    for (int d = 1; d < 256; d <<= 1) {
        int x = (tid >= d) ? lds[tid - d] : 0;
        __syncthreads();
        lds[tid] += x;
        __syncthreads();
    }
    int incl = lds[tid];
    int prefix = incl - s3;
    if (base + 0 < NN) offsets[base + 0] = prefix;
    if (base + 1 < NN) offsets[base + 1] = prefix + s0;
    if (base + 2 < NN) offsets[base + 2] = prefix + s1;
    if (base + 3 < NN) offsets[base + 3] = prefix + s2;
    if (tid == 255) totals[b] = lds[255];
}

__global__ void scan2(int* __restrict__ totals, int* __restrict__ offsets) {
    int run = 0;
    for (int b = 0; b < NBLK; ++b) { int x = totals[b]; totals[b] = run; run += x; }
    offsets[NN] = run;
}

__global__ __launch_bounds__(256) void scan3(int* __restrict__ offsets,
                                             const int* __restrict__ totals) {
    int i = blockIdx.x * 256 + threadIdx.x;
    if (i < NN) offsets[i] += totals[i >> 10];
}

__global__ __launch_bounds__(256) void fill_kernel(const int* __restrict__ src,
                                                   const int* __restrict__ dst,
                                                   const int* __restrict__ et,
                                                   const int* __restrict__ offsets,
                                                   int* __restrict__ cursor,
                                                   int* __restrict__ packed) {
    int e = blockIdx.x * 256 + threadIdx.x;
    if (e < EE) {
        int d = dst[e];
        int p = offsets[d] + atomicAdd(&cursor[d], 1);
        packed[p] = src[e] | (et[e] << 20);
    }
}

// ---------------- B convert: BT[n][k] = bf16(B[k][n]), k<512 from basis, else loopw ----------------

__global__ __launch_bounds__(256) void convertB(const float* __restrict__ basisflat, // [512][128]
                                                const float* __restrict__ loopw,     // [128][128]
                                                unsigned short* __restrict__ BT) {   // [128][640]
    int i = blockIdx.x * 256 + threadIdx.x;
    if (i >= 128 * 640) return;
    int n = i / 640, k = i % 640;
    float v = (k < 512) ? basisflat[(size_t)k * 128 + n] : loopw[(size_t)(k - 512) * 128 + n];
    BT[i] = bf16r(v);
}

// ---------------- input layer: hout = relu(feat @ win + bias), bf16 out ----------------

__global__ __launch_bounds__(256) void in_gemm(const float* __restrict__ feat,   // [N][128]
                                               const float* __restrict__ win,    // [128][128]
                                               const float* __restrict__ bias,   // [128]
                                               unsigned* __restrict__ hout) {    // [N][64] bf16x2
    __shared__ unsigned short A_lds[64][136];
    __shared__ float Bs[2][32][128];
    int tid = threadIdx.x;
    int nbase = blockIdx.x * 64;

#pragma unroll
    for (int q = 0; q < 8; ++q) {
        int lin = q * 256 + tid;
        int row = lin >> 5, c4 = (lin & 31) * 4;
        int grow = nbase + row;
        float4 v = make_float4(0.f, 0.f, 0.f, 0.f);
        if (grow < NN) v = *(const float4*)(feat + (size_t)grow * 128 + c4);
        unsigned* d = (unsigned*)&A_lds[row][c4];
        d[0] = pack2(v.x, v.y);
        d[1] = pack2(v.z, v.w);
    }
    int tc = tid & 31, tr = tid >> 5;
    float acc[8][4] = {};
    float4 breg[4];
#pragma unroll
    for (int q = 0; q < 4; ++q) {
        int lin = q * 256 + tid;
        breg[q] = *(const float4*)(win + (size_t)(lin >> 5) * 128 + (lin & 31) * 4);
    }
#pragma unroll
    for (int q = 0; q < 4; ++q) {
        int lin = q * 256 + tid;
        *(float4*)&Bs[0][lin >> 5][(lin & 31) * 4] = breg[q];
    }
    for (int c = 0; c < 4; ++c) {
        __syncthreads();
        if (c < 3) {
            const float* bsrc = win + (size_t)(c + 1) * 32 * 128;
#pragma unroll
            for (int q = 0; q < 4; ++q) {
                int lin = q * 256 + tid;
                breg[q] = *(const float4*)(bsrc + (size_t)(lin >> 5) * 128 + (lin & 31) * 4);
            }
        }
        int kloc = c * 32;
        const float(*Bcur)[128] = Bs[c & 1];
#pragma unroll
        for (int k8 = 0; k8 < 4; ++k8) {
            uint4 araw[8];
#pragma unroll
            for (int i = 0; i < 8; ++i)
                araw[i] = *(const uint4*)&A_lds[tr * 8 + i][kloc + k8 * 8];
#pragma unroll
            for (int kk = 0; kk < 8; ++kk) {
                float4 bv = *(const float4*)&Bcur[k8 * 8 + kk][tc * 4];
#pragma unroll
                for (int i = 0; i < 8; ++i) {
                    unsigned dw = ((const unsigned*)&araw[i])[kk >> 1];
                    float av = __uint_as_float((kk & 1) ? (dw & 0xffff0000u) : (dw << 16));
                    acc[i][0] = fmaf(av, bv.x, acc[i][0]);
                    acc[i][1] = fmaf(av, bv.y, acc[i][1]);
                    acc[i][2] = fmaf(av, bv.z, acc[i][2]);
                    acc[i][3] = fmaf(av, bv.w, acc[i][3]);
                }
            }
        }
        __syncthreads();
        if (c < 3) {
#pragma unroll
            for (int q = 0; q < 4; ++q) {
                int lin = q * 256 + tid;
                *(float4*)&Bs[(c + 1) & 1][lin >> 5][(lin & 31) * 4] = breg[q];
            }
        }
    }
    float4 bb = *(const float4*)(bias + tc * 4);
#pragma unroll
    for (int i = 0; i < 8; ++i) {
        int row = nbase + tr * 8 + i;
        if (row < NN) {
            float o0 = fmaxf(acc[i][0] + bb.x, 0.f);
            float o1 = fmaxf(acc[i][1] + bb.y, 0.f);
            float o2 = fmaxf(acc[i][2] + bb.z, 0.f);
            float o3 = fmaxf(acc[i][3] + bb.w, 0.f);
            hout[(size_t)row * 64 + tc * 2]     = pack2(o0, o1);
            hout[(size_t)row * 64 + tc * 2 + 1] = pack2(o2, o3);
        }
    }
}

// ---------------- aggregation: t[nl][512] bf16 = sum_e wcomp[et,:] (x) h[src] ----------------
// One wave per node, register accumulators, 4-edge unroll for MLP/ILP.

__global__ __launch_bounds__(256) void agg_kernel(const unsigned* __restrict__ hin, // [N][64] bf16x2
                                                  const int* __restrict__ offsets,
                                                  const int* __restrict__ packed,
                                                  const float* __restrict__ wcomp,  // [8][4]
                                                  unsigned* __restrict__ tbuf,      // [len][256]
                                                  int chunk_start, int chunk_len) {
    __shared__ float wc[32];
    int tid = threadIdx.x;
    if (tid < 32) wc[tid] = wcomp[tid];
    __syncthreads();
    int nl = blockIdx.x * 4 + (tid >> 6);
    int lane = tid & 63;
    if (nl >= chunk_len) return;
    int n = chunk_start + nl;
    int beg = offsets[n], end = offsets[n + 1];
    float a0x = 0.f, a0y = 0.f, a1x = 0.f, a1y = 0.f;
    float a2x = 0.f, a2y = 0.f, a3x = 0.f, a3y = 0.f;
    auto edge = [&](unsigned u, unsigned hv) {
        int r = (int)(u >> 20);
        float hx = __uint_as_float(hv << 16);
        float hy = __uint_as_float(hv & 0xffff0000u);
        float w0 = wc[r * 4 + 0], w1 = wc[r * 4 + 1];
        float w2 = wc[r * 4 + 2], w3 = wc[r * 4 + 3];
        a0x = fmaf(w0, hx, a0x); a0y = fmaf(w0, hy, a0y);
        a1x = fmaf(w1, hx, a1x); a1y = fmaf(w1, hy, a1y);
        a2x = fmaf(w2, hx, a2x); a2y = fmaf(w2, hy, a2y);
        a3x = fmaf(w3, hx, a3x); a3y = fmaf(w3, hy, a3y);
    };
    int e = beg;
    for (; e + 4 <= end; e += 4) {
        unsigned u0 = (unsigned)packed[e + 0];
        unsigned u1 = (unsigned)packed[e + 1];
        unsigned u2 = (unsigned)packed[e + 2];
        unsigned u3 = (unsigned)packed[e + 3];
        unsigned h0 = hin[(size_t)(u0 & 0xFFFFFu) * 64 + lane];
        unsigned h1 = hin[(size_t)(u1 & 0xFFFFFu) * 64 + lane];
        unsigned h2 = hin[(size_t)(u2 & 0xFFFFFu) * 64 + lane];
        unsigned h3 = hin[(size_t)(u3 & 0xFFFFFu) * 64 + lane];
        edge(u0, h0); edge(u1, h1); edge(u2, h2); edge(u3, h3);
    }
    for (; e < end; ++e) {
        unsigned u = (unsigned)packed[e];
        unsigned hv = hin[(size_t)(u & 0xFFFFFu) * 64 + lane];
        edge(u, hv);
    }
    size_t tb = (size_t)nl * 256 + lane;
    tbuf[tb + 0]   = pack2(a0x, a0y);
    tbuf[tb + 64]  = pack2(a1x, a1y);
    tbuf[tb + 128] = pack2(a2x, a2y);
    tbuf[tb + 192] = pack2(a3x, a3y);
}

// ---------------- conv GEMM (MFMA): hout = relu([t|h] @ BT^T + hbias), bf16 out ----------------
// Tile 128x128, BK=64, 10 K-chunks (8 from t, 2 from h). 4 waves (2x2), reg-staged
// double-buffered LDS with XOR swizzle byte ^= (row&7)<<4.

__global__ __launch_bounds__(256) void conv_gemm(const unsigned* __restrict__ tbuf, // [len][256]
                                                 const unsigned* __restrict__ hin,  // [N][64]
                                                 const unsigned short* __restrict__ BT, // [128][640]
                                                 const float* __restrict__ hbias,   // [128]
                                                 unsigned* __restrict__ hout,       // [N][64]
                                                 int chunk_start, int chunk_len) {
    __shared__ char As[2][16384];
    __shared__ char Bs[2][16384];
    int tid = threadIdx.x;
    int lane = tid & 63;
    int wave = tid >> 6;
    int wm = wave >> 1, wn = wave & 1;
    int m0 = blockIdx.x * 128;

    uint4 areg[4], breg[4];

    auto loadA = [&](int c) {
#pragma unroll
        for (int q = 0; q < 4; ++q) {
            int lin = q * 256 + tid;
            int row = lin >> 3, slot = lin & 7;
            int lr = m0 + row;
            lr = (lr < chunk_len) ? lr : (chunk_len - 1);
            const char* srcp;
            if (c < 8)
                srcp = (const char*)(tbuf + (size_t)lr * 256) + c * 128 + slot * 16;
            else
                srcp = (const char*)(hin + (size_t)(chunk_start + lr) * 64) + (c - 8) * 128 + slot * 16;
            areg[q] = *(const uint4*)srcp;
        }
    };
    auto loadB = [&](int c) {
#pragma unroll
        for (int q = 0; q < 4; ++q) {
            int lin = q * 256 + tid;
            int n = lin >> 3, slot = lin & 7;
            breg[q] = *(const uint4*)((const char*)(BT + (size_t)n * 640) + c * 128 + slot * 16);
        }
    };

    f32x4 acc[4][4];
#pragma unroll
    for (int m = 0; m < 4; ++m)
#pragma unroll
        for (int n = 0; n < 4; ++n) acc[m][n] = (f32x4)0.f;

    loadA(0); loadB(0);
    int swz = (lane & 7) << 4;

    for (int c = 0; c < 10; ++c) {
        int buf = c & 1;
        // stage regs -> LDS (swizzled)
#pragma unroll
        for (int q = 0; q < 4; ++q) {
            int lin = q * 256 + tid;
            int row = lin >> 3, slot = lin & 7;
            int off = row * 128 + ((slot * 16) ^ ((row & 7) << 4));
            *(uint4*)(As[buf] + off) = areg[q];
            *(uint4*)(Bs[buf] + off) = breg[q];
        }
        __syncthreads();
        if (c < 9) { loadA(c + 1); loadB(c + 1); }  // overlap next-chunk loads with MFMA
#pragma unroll
        for (int ks = 0; ks < 2; ++ks) {
            short8 a[4], b[4];
            int kb = ks * 64 + (lane >> 4) * 16;
#pragma unroll
            for (int m = 0; m < 4; ++m) {
                int row = wm * 64 + m * 16 + (lane & 15);
                a[m] = *(const short8*)(As[buf] + row * 128 + (kb ^ swz));
            }
#pragma unroll
            for (int n = 0; n < 4; ++n) {
                int col = wn * 64 + n * 16 + (lane & 15);
                b[n] = *(const short8*)(Bs[buf] + col * 128 + (kb ^ swz));
            }
#pragma unroll
            for (int m = 0; m < 4; ++m)
#pragma unroll
                for (int n = 0; n < 4; ++n)
                    acc[m][n] = __builtin_amdgcn_mfma_f32_16x16x32_bf16(a[m], b[n], acc[m][n], 0, 0, 0);
        }
        // no end barrier needed: next iter writes the other buffer; its start-barrier
        // separates those writes from this iter's reads two iterations back.
        __syncthreads();
    }

    // epilogue: bias + relu + pack bf16x2, write hout
    int colbase = wn * 64 + (lane & 15);
    float bias_v[4];
#pragma unroll
    for (int n = 0; n < 4; ++n) bias_v[n] = hbias[colbase + n * 16];
#pragma unroll
    for (int m = 0; m < 4; ++m) {
        int rl0 = m0 + wm * 64 + m * 16 + ((lane >> 4) << 2);
#pragma unroll
        for (int n = 0; n < 4; ++n) {
            int col = colbase + n * 16;
#pragma unroll
            for (int q = 0; q < 4; ++q) {
                float v = fmaxf(acc[m][n][q] + bias_v[n], 0.f);
                float vo = __shfl_xor(v, 1);
                int lr = rl0 + q;
                if (((lane & 1) == 0) && lr < chunk_len) {
                    hout[(size_t)(chunk_start + lr) * 64 + (col >> 1)] = pack2(v, vo);
                }
            }
        }
    }
}

// ---------------- output layer: out = relu(h @ wout + bout), f32 out ----------------

__global__ __launch_bounds__(256) void out_gemm(const unsigned* __restrict__ hin,  // [N][64] bf16x2
                                                const float* __restrict__ wout,    // [128][64]
                                                const float* __restrict__ bout,    // [64]
                                                float* __restrict__ outp) {        // [N][64]
    __shared__ unsigned short A_lds[64][136];
    __shared__ float Bs[2][32][64];
    int tid = threadIdx.x;
    int nbase = blockIdx.x * 64;
#pragma unroll
    for (int q = 0; q < 16; ++q) {
        int lin = q * 256 + tid;
        int row = lin >> 6, cu = lin & 63;
        unsigned v = 0u;
        if (nbase + row < NN) v = hin[(size_t)(nbase + row) * 64 + cu];
        *(unsigned*)&A_lds[row][cu * 2] = v;
    }
    int tc = tid & 15, tr = tid >> 4;
    float acc[4][4] = {};
    float4 breg[2];
#pragma unroll
    for (int q = 0; q < 2; ++q) {
        int lin = q * 256 + tid;
        breg[q] = *(const float4*)(wout + (size_t)(lin >> 4) * 64 + (lin & 15) * 4);
    }
#pragma unroll
    for (int q = 0; q < 2; ++q) {
        int lin = q * 256 + tid;
        *(float4*)&Bs[0][lin >> 4][(lin & 15) * 4] = breg[q];
    }
    for (int c = 0; c < 4; ++c) {
        __syncthreads();
        if (c < 3) {
            const float* bsrc = wout + (size_t)(c + 1) * 32 * 64;
#pragma unroll
            for (int q = 0; q < 2; ++q) {
                int lin = q * 256 + tid;
                breg[q] = *(const float4*)(bsrc + (size_t)(lin >> 4) * 64 + (lin & 15) * 4);
            }
        }
        int kloc = c * 32;
        const float(*Bcur)[64] = Bs[c & 1];
#pragma unroll
        for (int k8 = 0; k8 < 4; ++k8) {
            uint4 araw[4];
#pragma unroll
            for (int i = 0; i < 4; ++i)
                araw[i] = *(const uint4*)&A_lds[tr * 4 + i][kloc + k8 * 8];
#pragma unroll
            for (int kk = 0; kk < 8; ++kk) {
                float4 bv = *(const float4*)&Bcur[k8 * 8 + kk][tc * 4];
#pragma unroll
                for (int i = 0; i < 4; ++i) {
                    unsigned dw = ((const unsigned*)&araw[i])[kk >> 1];
                    float av = __uint_as_float((kk & 1) ? (dw & 0xffff0000u) : (dw << 16));
                    acc[i][0] = fmaf(av, bv.x, acc[i][0]);
                    acc[i][1] = fmaf(av, bv.y, acc[i][1]);
                    acc[i][2] = fmaf(av, bv.z, acc[i][2]);
                    acc[i][3] = fmaf(av, bv.w, acc[i][3]);
                }
            }
        }
        __syncthreads();
        if (c < 3) {
#pragma unroll
            for (int q = 0; q < 2; ++q) {
                int lin = q * 256 + tid;
                *(float4*)&Bs[(c + 1) & 1][lin >> 4][(lin & 15) * 4] = breg[q];
            }
        }
    }
    float4 bb = *(const float4*)(bout + tc * 4);
#pragma unroll
    for (int i = 0; i < 4; ++i) {
        int row = nbase + tr * 4 + i;
        if (row < NN) {
            float4 o;
            o.x = fmaxf(acc[i][0] + bb.x, 0.f);
            o.y = fmaxf(acc[i][1] + bb.y, 0.f);
            o.z = fmaxf(acc[i][2] + bb.z, 0.f);
            o.w = fmaxf(acc[i][3] + bb.w, 0.f);
            *(float4*)(outp + (size_t)row * 64 + tc * 4) = o;
        }
    }
}

// ---------------- launch ----------------

static inline size_t align256(size_t x) { return (x + 255) & ~(size_t)255; }

extern "C" void kernel_launch(void* const* d_in, const int* in_sizes, int n_in,
                              void* d_out, int out_size, void* d_ws, size_t ws_size,
                              hipStream_t stream) {
    const float* feat   = (const float*)d_in[0];
    const float* win    = (const float*)d_in[1];
    const float* bin_   = (const float*)d_in[2];
    const float* basis0 = (const float*)d_in[3];
    const float* wcomp0 = (const float*)d_in[4];
    const float* loop0  = (const float*)d_in[5];
    const float* hbias0 = (const float*)d_in[6];
    const float* basis1 = (const float*)d_in[7];
    const float* wcomp1 = (const float*)d_in[8];
    const float* loop1  = (const float*)d_in[9];
    const float* hbias1 = (const float*)d_in[10];
    const float* wout   = (const float*)d_in[11];
    const float* bout   = (const float*)d_in[12];
    const int*   src    = (const int*)d_in[13];
    const int*   dst    = (const int*)d_in[14];
    const int*   etyp   = (const int*)d_in[15];
    float* outp = (float*)d_out;

    size_t off = 0;
    char* wsb = (char*)d_ws;
    auto walloc = [&](size_t bytes) { void* p = wsb + off; off += align256(bytes); return p; };
    unsigned* hA  = (unsigned*)walloc((size_t)NN * 64 * 4);     // 25.6 MB
    unsigned* hB  = (unsigned*)walloc((size_t)NN * 64 * 4);     // 25.6 MB
    int* offsets  = (int*)walloc((size_t)(NN + 1) * 4);
    int* counts   = (int*)walloc((size_t)NN * 4);
    int* cursor   = (int*)walloc((size_t)NN * 4);
    int* totals   = (int*)walloc((size_t)NBLK * 4);
    int* packed   = (int*)walloc((size_t)EE * 4);               // 6.4 MB
    unsigned short* BT0 = (unsigned short*)walloc((size_t)128 * 640 * 2);
    unsigned short* BT1 = (unsigned short*)walloc((size_t)128 * 640 * 2);
    size_t fixed = off;

    // choose t-chunking to fit workspace (deterministic: ws_size constant per run)
    int nchunk = 1;
    while (nchunk < 32) {
        size_t rows = (size_t)(NN + nchunk - 1) / nchunk;
        if (fixed + rows * 1024 <= ws_size) break;
        nchunk *= 2;
    }
    int chunk_rows = (NN + nchunk - 1) / nchunk;
    unsigned* tbuf = (unsigned*)(wsb + fixed);

    // CSR build
    hipMemsetAsync(counts, 0, (size_t)NN * 4, stream);
    hipMemsetAsync(cursor, 0, (size_t)NN * 4, stream);
    count_kernel<<<(EE + 255) / 256, 256, 0, stream>>>(dst, counts);
    scan1<<<NBLK, 256, 0, stream>>>(counts, offsets, totals);
    scan2<<<1, 1, 0, stream>>>(totals, offsets);
    scan3<<<(NN + 255) / 256, 256, 0, stream>>>(offsets, totals);
    fill_kernel<<<(EE + 255) / 256, 256, 0, stream>>>(src, dst, etyp, offsets, cursor, packed);

    // weight conversions
    convertB<<<(128 * 640 + 255) / 256, 256, 0, stream>>>(basis0, loop0, BT0);
    convertB<<<(128 * 640 + 255) / 256, 256, 0, stream>>>(basis1, loop1, BT1);

    // input layer
    in_gemm<<<(NN + 63) / 64, 256, 0, stream>>>(feat, win, bin_, hA);

    // conv layer 0: hA -> hB
    for (int s = 0; s < NN; s += chunk_rows) {
        int len = (NN - s < chunk_rows) ? (NN - s) : chunk_rows;
        agg_kernel<<<(len + 3) / 4, 256, 0, stream>>>(hA, offsets, packed, wcomp0, tbuf, s, len);
        conv_gemm<<<(len + 127) / 128, 256, 0, stream>>>(tbuf, hA, BT0, hbias0, hB, s, len);
    }
    // conv layer 1: hB -> hA
    for (int s = 0; s < NN; s += chunk_rows) {
        int len = (NN - s < chunk_rows) ? (NN - s) : chunk_rows;
        agg_kernel<<<(len + 3) / 4, 256, 0, stream>>>(hB, offsets, packed, wcomp1, tbuf, s, len);
        conv_gemm<<<(len + 127) / 128, 256, 0, stream>>>(tbuf, hB, BT1, hbias1, hA, s, len);
    }
    // output layer
    out_gemm<<<(NN + 63) / 64, 256, 0, stream>>>(hA, wout, bout, outp);
}

// Round 4
// 556.347 us; speedup vs baseline: 5.0672x; 1.1776x over previous
//
#include <hip/hip_runtime.h>

#define NN   100000
#define EE   1600000
constexpr int RR = 8;
constexpr int BBASES = 4;
constexpr int SCAN_CHUNK = 1024;
constexpr int NBLK = (NN + SCAN_CHUNK - 1) / SCAN_CHUNK; // 98

typedef __attribute__((ext_vector_type(8))) short short8;
typedef __attribute__((ext_vector_type(4))) float f32x4;

__device__ __forceinline__ unsigned pack2(float x, float y) {
    unsigned xu = __float_as_uint(x);
    unsigned yu = __float_as_uint(y);
    xu = (xu + 0x7fffu + ((xu >> 16) & 1u)) >> 16;
    yu = (yu + 0x7fffu + ((yu >> 16) & 1u)) & 0xffff0000u;
    return xu | yu;
}

__device__ __forceinline__ unsigned short bf16r(float x) {
    unsigned u = __float_as_uint(x);
    return (unsigned short)((u + 0x7fffu + ((u >> 16) & 1u)) >> 16);
}

// ---------------- CSR build ----------------

__global__ __launch_bounds__(256) void count_kernel(const int* __restrict__ dst,
                                                    int* __restrict__ counts) {
    int e = blockIdx.x * 256 + threadIdx.x;
    if (e < EE) atomicAdd(&counts[dst[e]], 1);
}

__global__ __launch_bounds__(256) void scan1(const int* __restrict__ counts,
                                             int* __restrict__ offsets,
                                             int* __restrict__ totals) {
    __shared__ int lds[256];
    int b = blockIdx.x, tid = threadIdx.x;
    int base = b * SCAN_CHUNK + tid * 4;
    int v0 = (base + 0 < NN) ? counts[base + 0] : 0;
    int v1 = (base + 1 < NN) ? counts[base + 1] : 0;
    int v2 = (base + 2 < NN) ? counts[base + 2] : 0;
    int v3 = (base + 3 < NN) ? counts[base + 3] : 0;
    int s0 = v0, s1 = s0 + v1, s2 = s1 + v2, s3 = s2 + v3;
    lds[tid] = s3;
    __syncthreads();
    for (int d = 1; d < 256; d <<= 1) {
        int x = (tid >= d) ? lds[tid - d] : 0;
        __syncthreads();
        lds[tid] += x;
        __syncthreads();
    }
    int incl = lds[tid];
    int prefix = incl - s3;
    if (base + 0 < NN) offsets[base + 0] = prefix;
    if (base + 1 < NN) offsets[base + 1] = prefix + s0;
    if (base + 2 < NN) offsets[base + 2] = prefix + s1;
    if (base + 3 < NN) offsets[base + 3] = prefix + s2;
    if (tid == 255) totals[b] = lds[255];
}

__global__ void scan2(int* __restrict__ totals, int* __restrict__ offsets) {
    int run = 0;
    for (int b = 0; b < NBLK; ++b) { int x = totals[b]; totals[b] = run; run += x; }
    offsets[NN] = run;
}

__global__ __launch_bounds__(256) void scan3(int* __restrict__ offsets,
                                             const int* __restrict__ totals) {
    int i = blockIdx.x * 256 + threadIdx.x;
    if (i < NN) offsets[i] += totals[i >> 10];
}

__global__ __launch_bounds__(256) void fill_kernel(const int* __restrict__ src,
                                                   const int* __restrict__ dst,
                                                   const int* __restrict__ et,
                                                   const int* __restrict__ offsets,
                                                   int* __restrict__ cursor,
                                                   int* __restrict__ packed) {
    int e = blockIdx.x * 256 + threadIdx.x;
    if (e < EE) {
        int d = dst[e];
        int p = offsets[d] + atomicAdd(&cursor[d], 1);
        packed[p] = src[e] | (et[e] << 20);
    }
}

// ---------------- weight/feature conversions ----------------

// BT[n][k] = bf16(B[k][n]), k<512 basis, else loopw  -> [128][640]
__global__ __launch_bounds__(256) void convertB(const float* __restrict__ basisflat,
                                                const float* __restrict__ loopw,
                                                unsigned short* __restrict__ BT) {
    int i = blockIdx.x * 256 + threadIdx.x;
    if (i >= 128 * 640) return;
    int n = i / 640, k = i % 640;
    float v = (k < 512) ? basisflat[(size_t)k * 128 + n] : loopw[(size_t)(k - 512) * 128 + n];
    BT[i] = bf16r(v);
}

// WT[n][k] = bf16(W[k][n]); W is [128][nc]
__global__ __launch_bounds__(256) void convertWT(const float* __restrict__ W,
                                                 unsigned short* __restrict__ WT, int nc) {
    int i = blockIdx.x * 256 + threadIdx.x;
    if (i >= nc * 128) return;
    int n = i >> 7, k = i & 127;
    WT[i] = bf16r(W[(size_t)k * nc + n]);
}

// featb[i] = pack2(feat[2i], feat[2i+1])  (N*64 u32)
__global__ __launch_bounds__(256) void convert_feat(const float* __restrict__ feat,
                                                    unsigned* __restrict__ featb) {
    int i = blockIdx.x * 256 + threadIdx.x;
    if (i < NN * 64) {
        float2 v = *(const float2*)(feat + (size_t)i * 2);
        featb[i] = pack2(v.x, v.y);
    }
}

// ---------------- generic MFMA GEMM, K=128: out = relu(A @ BT^T + bias) ----------------
// A: [M][64] bf16x2. BT: [NC][128] bf16. Tile 128 x NC, BK=64 (2 chunks), 4 waves 2x2,
// XOR-swizzled double-buffered LDS (same structure as conv_gemm).
template <int NC, bool F32OUT>
__global__ __launch_bounds__(256) void gemm128(const unsigned* __restrict__ Ab,
                                               const unsigned short* __restrict__ BT,
                                               const float* __restrict__ bias,
                                               void* __restrict__ outp, int M) {
    constexpr int NFRAG = NC / 32;
    constexpr int BQ = NC * 8 / 256;
    __shared__ char As[2][16384];
    __shared__ char Bs[2][NC * 128];
    int tid = threadIdx.x;
    int lane = tid & 63;
    int wave = tid >> 6;
    int wm = wave >> 1, wn = wave & 1;
    int m0 = blockIdx.x * 128;

    uint4 areg[4], breg[BQ];
    auto loadA = [&](int c) {
#pragma unroll
        for (int q = 0; q < 4; ++q) {
            int lin = q * 256 + tid;
            int row = lin >> 3, slot = lin & 7;
            int gr = m0 + row;
            gr = (gr < M) ? gr : (M - 1);
            areg[q] = *(const uint4*)((const char*)(Ab + (size_t)gr * 64) + c * 128 + slot * 16);
        }
    };
    auto loadB = [&](int c) {
#pragma unroll
        for (int q = 0; q < BQ; ++q) {
            int lin = q * 256 + tid;
            int n = lin >> 3, slot = lin & 7;
            breg[q] = *(const uint4*)((const char*)BT + (size_t)n * 256 + c * 128 + slot * 16);
        }
    };

    f32x4 acc[4][NFRAG];
#pragma unroll
    for (int m = 0; m < 4; ++m)
#pragma unroll
        for (int n = 0; n < NFRAG; ++n) acc[m][n] = (f32x4)0.f;

    loadA(0); loadB(0);
    int swz = (lane & 7) << 4;

    for (int c = 0; c < 2; ++c) {
        int buf = c & 1;
#pragma unroll
        for (int q = 0; q < 4; ++q) {
            int lin = q * 256 + tid;
            int row = lin >> 3, slot = lin & 7;
            *(uint4*)(As[buf] + row * 128 + ((slot * 16) ^ ((row & 7) << 4))) = areg[q];
        }
#pragma unroll
        for (int q = 0; q < BQ; ++q) {
            int lin = q * 256 + tid;
            int row = lin >> 3, slot = lin & 7;
            *(uint4*)(Bs[buf] + row * 128 + ((slot * 16) ^ ((row & 7) << 4))) = breg[q];
        }
        __syncthreads();
        if (c < 1) { loadA(1); loadB(1); }
#pragma unroll
        for (int ks = 0; ks < 2; ++ks) {
            short8 a[4], b[NFRAG];
            int kb = ks * 64 + (lane >> 4) * 16;
#pragma unroll
            for (int m = 0; m < 4; ++m) {
                int row = wm * 64 + m * 16 + (lane & 15);
                a[m] = *(const short8*)(As[buf] + row * 128 + (kb ^ swz));
            }
#pragma unroll
            for (int n = 0; n < NFRAG; ++n) {
                int col = wn * (NC / 2) + n * 16 + (lane & 15);
                b[n] = *(const short8*)(Bs[buf] + col * 128 + (kb ^ swz));
            }
#pragma unroll
            for (int m = 0; m < 4; ++m)
#pragma unroll
                for (int n = 0; n < NFRAG; ++n)
                    acc[m][n] = __builtin_amdgcn_mfma_f32_16x16x32_bf16(a[m], b[n], acc[m][n], 0, 0, 0);
        }
        __syncthreads();
    }

    int colbase = wn * (NC / 2) + (lane & 15);
    float bias_v[NFRAG];
#pragma unroll
    for (int n = 0; n < NFRAG; ++n) bias_v[n] = bias[colbase + n * 16];
#pragma unroll
    for (int m = 0; m < 4; ++m) {
        int rl0 = m0 + wm * 64 + m * 16 + ((lane >> 4) << 2);
#pragma unroll
        for (int n = 0; n < NFRAG; ++n) {
            int col = colbase + n * 16;
#pragma unroll
            for (int q = 0; q < 4; ++q) {
                float v = fmaxf(acc[m][n][q] + bias_v[n], 0.f);
                int row = rl0 + q;
                if (F32OUT) {
                    if (row < M) ((float*)outp)[(size_t)row * NC + col] = v;
                } else {
                    float vo = __shfl_xor(v, 1);
                    if (((lane & 1) == 0) && row < M)
                        ((unsigned*)outp)[(size_t)row * (NC / 2) + (col >> 1)] = pack2(v, vo);
                }
            }
        }
    }
}

// ---------------- aggregation: t[nl][512] bf16 = sum_e wcomp[et,:] (x) h[src] ----------------

__global__ __launch_bounds__(256) void agg_kernel(const unsigned* __restrict__ hin, // [N][64] bf16x2
                                                  const int* __restrict__ offsets,
                                                  const int* __restrict__ packed,
                                                  const float* __restrict__ wcomp,  // [8][4]
                                                  unsigned* __restrict__ tbuf,      // [len][256]
                                                  int chunk_start, int chunk_len) {
    __shared__ float wc[32];
    int tid = threadIdx.x;
    if (tid < 32) wc[tid] = wcomp[tid];
    __syncthreads();
    int nl = blockIdx.x * 4 + (tid >> 6);
    int lane = tid & 63;
    if (nl >= chunk_len) return;
    int n = chunk_start + nl;
    int beg = offsets[n], end = offsets[n + 1];
    float a0x = 0.f, a0y = 0.f, a1x = 0.f, a1y = 0.f;
    float a2x = 0.f, a2y = 0.f, a3x = 0.f, a3y = 0.f;
    auto edge = [&](unsigned u, unsigned hv) {
        int r = (int)(u >> 20);
        float hx = __uint_as_float(hv << 16);
        float hy = __uint_as_float(hv & 0xffff0000u);
        float w0 = wc[r * 4 + 0], w1 = wc[r * 4 + 1];
        float w2 = wc[r * 4 + 2], w3 = wc[r * 4 + 3];
        a0x = fmaf(w0, hx, a0x); a0y = fmaf(w0, hy, a0y);
        a1x = fmaf(w1, hx, a1x); a1y = fmaf(w1, hy, a1y);
        a2x = fmaf(w2, hx, a2x); a2y = fmaf(w2, hy, a2y);
        a3x = fmaf(w3, hx, a3x); a3y = fmaf(w3, hy, a3y);
    };
    int e = beg;
    for (; e + 4 <= end; e += 4) {
        unsigned u0 = (unsigned)packed[e + 0];
        unsigned u1 = (unsigned)packed[e + 1];
        unsigned u2 = (unsigned)packed[e + 2];
        unsigned u3 = (unsigned)packed[e + 3];
        unsigned h0 = hin[(size_t)(u0 & 0xFFFFFu) * 64 + lane];
        unsigned h1 = hin[(size_t)(u1 & 0xFFFFFu) * 64 + lane];
        unsigned h2 = hin[(size_t)(u2 & 0xFFFFFu) * 64 + lane];
        unsigned h3 = hin[(size_t)(u3 & 0xFFFFFu) * 64 + lane];
        edge(u0, h0); edge(u1, h1); edge(u2, h2); edge(u3, h3);
    }
    for (; e < end; ++e) {
        unsigned u = (unsigned)packed[e];
        unsigned hv = hin[(size_t)(u & 0xFFFFFu) * 64 + lane];
        edge(u, hv);
    }
    size_t tb = (size_t)nl * 256 + lane;
    tbuf[tb + 0]   = pack2(a0x, a0y);
    tbuf[tb + 64]  = pack2(a1x, a1y);
    tbuf[tb + 128] = pack2(a2x, a2y);
    tbuf[tb + 192] = pack2(a3x, a3y);
}

// ---------------- conv GEMM (MFMA): hout = relu([t|h] @ BT^T + hbias), bf16 out ----------------

__global__ __launch_bounds__(256) void conv_gemm(const unsigned* __restrict__ tbuf, // [len][256]
                                                 const unsigned* __restrict__ hin,  // [N][64]
                                                 const unsigned short* __restrict__ BT, // [128][640]
                                                 const float* __restrict__ hbias,   // [128]
                                                 unsigned* __restrict__ hout,       // [N][64]
                                                 int chunk_start, int chunk_len) {
    __shared__ char As[2][16384];
    __shared__ char Bs[2][16384];
    int tid = threadIdx.x;
    int lane = tid & 63;
    int wave = tid >> 6;
    int wm = wave >> 1, wn = wave & 1;
    int m0 = blockIdx.x * 128;

    uint4 areg[4], breg[4];

    auto loadA = [&](int c) {
#pragma unroll
        for (int q = 0; q < 4; ++q) {
            int lin = q * 256 + tid;
            int row = lin >> 3, slot = lin & 7;
            int lr = m0 + row;
            lr = (lr < chunk_len) ? lr : (chunk_len - 1);
            const char* srcp;
            if (c < 8)
                srcp = (const char*)(tbuf + (size_t)lr * 256) + c * 128 + slot * 16;
            else
                srcp = (const char*)(hin + (size_t)(chunk_start + lr) * 64) + (c - 8) * 128 + slot * 16;
            areg[q] = *(const uint4*)srcp;
        }
    };
    auto loadB = [&](int c) {
#pragma unroll
        for (int q = 0; q < 4; ++q) {
            int lin = q * 256 + tid;
            int n = lin >> 3, slot = lin & 7;
            breg[q] = *(const uint4*)((const char*)(BT + (size_t)n * 640) + c * 128 + slot * 16);
        }
    };

    f32x4 acc[4][4];
#pragma unroll
    for (int m = 0; m < 4; ++m)
#pragma unroll
        for (int n = 0; n < 4; ++n) acc[m][n] = (f32x4)0.f;

    loadA(0); loadB(0);
    int swz = (lane & 7) << 4;

    for (int c = 0; c < 10; ++c) {
        int buf = c & 1;
#pragma unroll
        for (int q = 0; q < 4; ++q) {
            int lin = q * 256 + tid;
            int row = lin >> 3, slot = lin & 7;
            int off = row * 128 + ((slot * 16) ^ ((row & 7) << 4));
            *(uint4*)(As[buf] + off) = areg[q];
            *(uint4*)(Bs[buf] + off) = breg[q];
        }
        __syncthreads();
        if (c < 9) { loadA(c + 1); loadB(c + 1); }
#pragma unroll
        for (int ks = 0; ks < 2; ++ks) {
            short8 a[4], b[4];
            int kb = ks * 64 + (lane >> 4) * 16;
#pragma unroll
            for (int m = 0; m < 4; ++m) {
                int row = wm * 64 + m * 16 + (lane & 15);
                a[m] = *(const short8*)(As[buf] + row * 128 + (kb ^ swz));
            }
#pragma unroll
            for (int n = 0; n < 4; ++n) {
                int col = wn * 64 + n * 16 + (lane & 15);
                b[n] = *(const short8*)(Bs[buf] + col * 128 + (kb ^ swz));
            }
#pragma unroll
            for (int m = 0; m < 4; ++m)
#pragma unroll
                for (int n = 0; n < 4; ++n)
                    acc[m][n] = __builtin_amdgcn_mfma_f32_16x16x32_bf16(a[m], b[n], acc[m][n], 0, 0, 0);
        }
        __syncthreads();
    }

    int colbase = wn * 64 + (lane & 15);
    float bias_v[4];
#pragma unroll
    for (int n = 0; n < 4; ++n) bias_v[n] = hbias[colbase + n * 16];
#pragma unroll
    for (int m = 0; m < 4; ++m) {
        int rl0 = m0 + wm * 64 + m * 16 + ((lane >> 4) << 2);
#pragma unroll
        for (int n = 0; n < 4; ++n) {
            int col = colbase + n * 16;
#pragma unroll
            for (int q = 0; q < 4; ++q) {
                float v = fmaxf(acc[m][n][q] + bias_v[n], 0.f);
                float vo = __shfl_xor(v, 1);
                int lr = rl0 + q;
                if (((lane & 1) == 0) && lr < chunk_len) {
                    hout[(size_t)(chunk_start + lr) * 64 + (col >> 1)] = pack2(v, vo);
                }
            }
        }
    }
}

// ---------------- launch ----------------

static inline size_t align256(size_t x) { return (x + 255) & ~(size_t)255; }

extern "C" void kernel_launch(void* const* d_in, const int* in_sizes, int n_in,
                              void* d_out, int out_size, void* d_ws, size_t ws_size,
                              hipStream_t stream) {
    const float* feat   = (const float*)d_in[0];
    const float* win    = (const float*)d_in[1];
    const float* bin_   = (const float*)d_in[2];
    const float* basis0 = (const float*)d_in[3];
    const float* wcomp0 = (const float*)d_in[4];
    const float* loop0  = (const float*)d_in[5];
    const float* hbias0 = (const float*)d_in[6];
    const float* basis1 = (const float*)d_in[7];
    const float* wcomp1 = (const float*)d_in[8];
    const float* loop1  = (const float*)d_in[9];
    const float* hbias1 = (const float*)d_in[10];
    const float* wout   = (const float*)d_in[11];
    const float* bout   = (const float*)d_in[12];
    const int*   src    = (const int*)d_in[13];
    const int*   dst    = (const int*)d_in[14];
    const int*   etyp   = (const int*)d_in[15];
    float* outp = (float*)d_out;

    size_t off = 0;
    char* wsb = (char*)d_ws;
    auto walloc = [&](size_t bytes) { void* p = wsb + off; off += align256(bytes); return p; };
    unsigned* hA  = (unsigned*)walloc((size_t)NN * 64 * 4);     // 25.6 MB
    unsigned* hB  = (unsigned*)walloc((size_t)NN * 64 * 4);     // 25.6 MB
    unsigned* featb = (unsigned*)walloc((size_t)NN * 64 * 4);   // 25.6 MB
    int* offsets  = (int*)walloc((size_t)(NN + 1) * 4);
    int* counts   = (int*)walloc((size_t)NN * 4);
    int* cursor   = (int*)walloc((size_t)NN * 4);
    int* totals   = (int*)walloc((size_t)NBLK * 4);
    int* packed   = (int*)walloc((size_t)EE * 4);               // 6.4 MB
    unsigned short* BT0 = (unsigned short*)walloc((size_t)128 * 640 * 2);
    unsigned short* BT1 = (unsigned short*)walloc((size_t)128 * 640 * 2);
    unsigned short* winT = (unsigned short*)walloc((size_t)128 * 128 * 2);
    unsigned short* woutT = (unsigned short*)walloc((size_t)64 * 128 * 2);
    size_t fixed = off;

    int nchunk = 1;
    while (nchunk < 32) {
        size_t rows = (size_t)(NN + nchunk - 1) / nchunk;
        if (fixed + rows * 1024 <= ws_size) break;
        nchunk *= 2;
    }
    int chunk_rows = (NN + nchunk - 1) / nchunk;
    unsigned* tbuf = (unsigned*)(wsb + fixed);

    // CSR build
    hipMemsetAsync(counts, 0, (size_t)NN * 4, stream);
    hipMemsetAsync(cursor, 0, (size_t)NN * 4, stream);
    count_kernel<<<(EE + 255) / 256, 256, 0, stream>>>(dst, counts);
    scan1<<<NBLK, 256, 0, stream>>>(counts, offsets, totals);
    scan2<<<1, 1, 0, stream>>>(totals, offsets);
    scan3<<<(NN + 255) / 256, 256, 0, stream>>>(offsets, totals);
    fill_kernel<<<(EE + 255) / 256, 256, 0, stream>>>(src, dst, etyp, offsets, cursor, packed);

    // weight/feature conversions
    convertB<<<(128 * 640 + 255) / 256, 256, 0, stream>>>(basis0, loop0, BT0);
    convertB<<<(128 * 640 + 255) / 256, 256, 0, stream>>>(basis1, loop1, BT1);
    convertWT<<<(128 * 128 + 255) / 256, 256, 0, stream>>>(win, winT, 128);
    convertWT<<<(64 * 128 + 255) / 256, 256, 0, stream>>>(wout, woutT, 64);
    convert_feat<<<(NN * 64 + 255) / 256, 256, 0, stream>>>(feat, featb);

    int gblocks = (NN + 127) / 128;  // 782
    // input layer (MFMA): hA = relu(featb @ winT^T + bin_)
    gemm128<128, false><<<gblocks, 256, 0, stream>>>(featb, winT, bin_, hA, NN);

    // conv layer 0: hA -> hB
    for (int s = 0; s < NN; s += chunk_rows) {
        int len = (NN - s < chunk_rows) ? (NN - s) : chunk_rows;
        agg_kernel<<<(len + 3) / 4, 256, 0, stream>>>(hA, offsets, packed, wcomp0, tbuf, s, len);
        conv_gemm<<<(len + 127) / 128, 256, 0, stream>>>(tbuf, hA, BT0, hbias0, hB, s, len);
    }
    // conv layer 1: hB -> hA
    for (int s = 0; s < NN; s += chunk_rows) {
        int len = (NN - s < chunk_rows) ? (NN - s) : chunk_rows;
        agg_kernel<<<(len + 3) / 4, 256, 0, stream>>>(hB, offsets, packed, wcomp1, tbuf, s, len);
        conv_gemm<<<(len + 127) / 128, 256, 0, stream>>>(tbuf, hB, BT1, hbias1, hA, s, len);
    }
    // output layer (MFMA): out = relu(hA @ woutT^T + bout), f32
    gemm128<64, true><<<gblocks, 256, 0, stream>>>(hA, woutT, bout, outp, NN);
}

// Round 6
// 491.600 us; speedup vs baseline: 5.7346x; 1.1317x over previous
//
#include <hip/hip_runtime.h>

#define NN   100000
#define EE   1600000
constexpr int RR = 8;
constexpr int BBASES = 4;
constexpr int SCAN_CHUNK = 1024;
constexpr int NBLK = (NN + SCAN_CHUNK - 1) / SCAN_CHUNK; // 98
constexpr int NBUK = 98;                                 // coarse buckets (dst>>10)
constexpr int EPB  = 4096;                               // edges per bin_pass1 block
constexpr int P1BLOCKS = (EE + EPB - 1) / EPB;           // 391

typedef __attribute__((ext_vector_type(8))) short short8;
typedef __attribute__((ext_vector_type(4))) float f32x4;

__device__ __forceinline__ unsigned pack2(float x, float y) {
    unsigned xu = __float_as_uint(x);
    unsigned yu = __float_as_uint(y);
    xu = (xu + 0x7fffu + ((xu >> 16) & 1u)) >> 16;
    yu = (yu + 0x7fffu + ((yu >> 16) & 1u)) & 0xffff0000u;
    return xu | yu;
}

__device__ __forceinline__ unsigned short bf16r(float x) {
    unsigned u = __float_as_uint(x);
    return (unsigned short)((u + 0x7fffu + ((u >> 16) & 1u)) >> 16);
}

// ---------------- CSR build: count + scan ----------------

__global__ __launch_bounds__(256) void count_kernel(const int* __restrict__ dst,
                                                    int* __restrict__ counts) {
    int e = blockIdx.x * 256 + threadIdx.x;
    if (e < EE) atomicAdd(&counts[dst[e]], 1);
}

__global__ __launch_bounds__(256) void scan1(const int* __restrict__ counts,
                                             int* __restrict__ offsets,
                                             int* __restrict__ totals) {
    __shared__ int lds[256];
    int b = blockIdx.x, tid = threadIdx.x;
    int base = b * SCAN_CHUNK + tid * 4;
    int v0 = (base + 0 < NN) ? counts[base + 0] : 0;
    int v1 = (base + 1 < NN) ? counts[base + 1] : 0;
    int v2 = (base + 2 < NN) ? counts[base + 2] : 0;
    int v3 = (base + 3 < NN) ? counts[base + 3] : 0;
    int s0 = v0, s1 = s0 + v1, s2 = s1 + v2, s3 = s2 + v3;
    lds[tid] = s3;
    __syncthreads();
    for (int d = 1; d < 256; d <<= 1) {
        int x = (tid >= d) ? lds[tid - d] : 0;
        __syncthreads();
        lds[tid] += x;
        __syncthreads();
    }
    int incl = lds[tid];
    int prefix = incl - s3;
    if (base + 0 < NN) offsets[base + 0] = prefix;
    if (base + 1 < NN) offsets[base + 1] = prefix + s0;
    if (base + 2 < NN) offsets[base + 2] = prefix + s1;
    if (base + 3 < NN) offsets[base + 3] = prefix + s2;
    if (tid == 255) totals[b] = lds[255];
}

__global__ void scan2(int* __restrict__ totals, int* __restrict__ offsets) {
    int run = 0;
    for (int b = 0; b < NBLK; ++b) { int x = totals[b]; totals[b] = run; run += x; }
    offsets[NN] = run;
}

__global__ __launch_bounds__(256) void scan3(int* __restrict__ offsets,
                                             const int* __restrict__ totals) {
    int i = blockIdx.x * 256 + threadIdx.x;
    if (i < NN) offsets[i] += totals[i >> 10];
}

__global__ void init_cursor(const int* __restrict__ offsets, int* __restrict__ gcursor) {
    int b = threadIdx.x;
    if (b < NBUK) gcursor[b] = offsets[b << 10];
}

// ---------------- edge binning (replaces scatter fill) ----------------
// pass1: block-local histogram + LDS reorder -> contiguous run copies into tmp
// word layout in tmp: bits[16:0]=src, [19:17]=etype, [29:20]=dst&1023

__global__ __launch_bounds__(256) void bin_pass1(const int* __restrict__ src,
                                                 const int* __restrict__ dst,
                                                 const int* __restrict__ et,
                                                 int* __restrict__ gcursor,
                                                 unsigned* __restrict__ tmp) {
    __shared__ unsigned stage[EPB];   // 16 KB
    __shared__ int hist[128];
    __shared__ int sc[128];
    __shared__ int lb[128];
    __shared__ int gb[128];
    int tid = threadIdx.x;
    long e0 = (long)blockIdx.x * EPB;
    if (tid < 128) hist[tid] = 0;
    __syncthreads();

    unsigned w[16];
    int bk[16], pos[16];
#pragma unroll
    for (int i = 0; i < 16; ++i) {
        long e = e0 + i * 256 + tid;
        bool valid = e < EE;
        int d = valid ? dst[e] : 0;
        int s = valid ? src[e] : 0;
        int r = valid ? et[e] : 0;
        bk[i] = d >> 10;
        w[i] = (unsigned)s | ((unsigned)r << 17) | ((unsigned)(d & 1023) << 20);
        pos[i] = valid ? atomicAdd(&hist[bk[i]], 1) : -1;
    }
    __syncthreads();
    // inclusive scan of hist[0..127] (entries >= NBUK are zero)
    if (tid < 128) sc[tid] = hist[tid];
    __syncthreads();
    for (int d = 1; d < 128; d <<= 1) {
        int v = 0;
        if (tid < 128 && tid >= d) v = sc[tid - d];
        __syncthreads();
        if (tid < 128) sc[tid] += v;
        __syncthreads();
    }
    if (tid < 128) lb[tid] = sc[tid] - hist[tid];   // exclusive base
    if (tid < NBUK && hist[tid] > 0) gb[tid] = atomicAdd(&gcursor[tid], hist[tid]);
    __syncthreads();
    int total = sc[127];
#pragma unroll
    for (int i = 0; i < 16; ++i) {
        if (pos[i] >= 0) stage[lb[bk[i]] + pos[i]] = w[i];
    }
    __syncthreads();
    // copy runs out: slot s belongs to bucket j = max{j : lb[j] <= s}
    for (int s = tid; s < total; s += 256) {
        int lo = 0, hi = 127;
#pragma unroll
        for (int it = 0; it < 7; ++it) {
            int mid = (lo + hi + 1) >> 1;
            if (lb[mid] <= s) lo = mid; else hi = mid - 1;
        }
        tmp[gb[lo] + (s - lb[lo])] = stage[s];
    }
}

// pass2: one block per bucket; exact per-node placement via LDS cursors
__global__ __launch_bounds__(1024) void bin_pass2(const unsigned* __restrict__ tmp,
                                                  const int* __restrict__ offsets,
                                                  int* __restrict__ packed) {
    __shared__ int cur[1024];
    __shared__ int offs[1025];
    int b = blockIdx.x, tid = threadIdx.x;
    int nb0 = b << 10;
    int nend = nb0 + 1024; if (nend > NN) nend = NN;
    int nloc = nend - nb0;
    cur[tid] = 0;
    for (int i = tid; i <= nloc; i += 1024) offs[i] = offsets[nb0 + i];  // covers offs[1024]
    __syncthreads();
    int beg = offs[0], end = offs[nloc];
    for (int e = beg + tid; e < end; e += 1024) {
        unsigned wv = tmp[e];
        int dl = (wv >> 20) & 1023;
        int p = offs[dl] + atomicAdd(&cur[dl], 1);
        packed[p] = (int)((wv & 0x1FFFFu) | (((wv >> 17) & 7u) << 20));
    }
}

// ---------------- weight conversions (merged) ----------------

__global__ __launch_bounds__(256) void convert_weights(const float* __restrict__ basis0,
                                                       const float* __restrict__ loop0,
                                                       const float* __restrict__ basis1,
                                                       const float* __restrict__ loop1,
                                                       const float* __restrict__ win,
                                                       const float* __restrict__ wout,
                                                       unsigned short* __restrict__ BT0,
                                                       unsigned short* __restrict__ BT1,
                                                       unsigned short* __restrict__ winT,
                                                       unsigned short* __restrict__ woutT) {
    int i = blockIdx.x * 256 + threadIdx.x;
    if (i < 81920) {
        int n = i / 640, k = i % 640;
        BT0[i] = bf16r(k < 512 ? basis0[(size_t)k * 128 + n] : loop0[(size_t)(k - 512) * 128 + n]);
    } else if (i < 163840) {
        int j = i - 81920;
        int n = j / 640, k = j % 640;
        BT1[j] = bf16r(k < 512 ? basis1[(size_t)k * 128 + n] : loop1[(size_t)(k - 512) * 128 + n]);
    } else if (i < 180224) {
        int j = i - 163840;
        int n = j >> 7, k = j & 127;
        winT[j] = bf16r(win[(size_t)k * 128 + n]);
    } else if (i < 188416) {
        int j = i - 180224;
        int n = j >> 7, k = j & 127;
        woutT[j] = bf16r(wout[(size_t)k * 64 + n]);
    }
}

// ---------------- generic MFMA GEMM, K=128: out = relu(A @ BT^T + bias) ----------------
// A: bf16x2 [M][64] (AF32=false) or f32 [M][128] (AF32=true, converted while staging).
template <int NC, bool F32OUT, bool AF32>
__global__ __launch_bounds__(256) void gemm128(const void* __restrict__ Aptr,
                                               const unsigned short* __restrict__ BT,
                                               const float* __restrict__ bias,
                                               void* __restrict__ outp, int M) {
    constexpr int NFRAG = NC / 32;
    constexpr int BQ = NC * 8 / 256;
    __shared__ char As[2][16384];
    __shared__ char Bs[2][NC * 128];
    int tid = threadIdx.x;
    int lane = tid & 63;
    int wave = tid >> 6;
    int wm = wave >> 1, wn = wave & 1;
    int m0 = blockIdx.x * 128;

    uint4 areg[4], breg[BQ];
    auto loadA = [&](int c) {
#pragma unroll
        for (int q = 0; q < 4; ++q) {
            int lin = q * 256 + tid;
            int row = lin >> 3, slot = lin & 7;
            int gr = m0 + row;
            gr = (gr < M) ? gr : (M - 1);
            if (AF32) {
                const float* fp = (const float*)Aptr + (size_t)gr * 128 + c * 64 + slot * 8;
                float4 v0 = *(const float4*)fp;
                float4 v1 = *(const float4*)(fp + 4);
                areg[q].x = pack2(v0.x, v0.y);
                areg[q].y = pack2(v0.z, v0.w);
                areg[q].z = pack2(v1.x, v1.y);
                areg[q].w = pack2(v1.z, v1.w);
            } else {
                areg[q] = *(const uint4*)((const char*)Aptr + (size_t)gr * 256 + c * 128 + slot * 16);
            }
        }
    };
    auto loadB = [&](int c) {
#pragma unroll
        for (int q = 0; q < BQ; ++q) {
            int lin = q * 256 + tid;
            int n = lin >> 3, slot = lin & 7;
            breg[q] = *(const uint4*)((const char*)BT + (size_t)n * 256 + c * 128 + slot * 16);
        }
    };

    f32x4 acc[4][NFRAG];
#pragma unroll
    for (int m = 0; m < 4; ++m)
#pragma unroll
        for (int n = 0; n < NFRAG; ++n) acc[m][n] = (f32x4)0.f;

    loadA(0); loadB(0);
    int swz = (lane & 7) << 4;

    for (int c = 0; c < 2; ++c) {
        int buf = c & 1;
#pragma unroll
        for (int q = 0; q < 4; ++q) {
            int lin = q * 256 + tid;
            int row = lin >> 3, slot = lin & 7;
            *(uint4*)(As[buf] + row * 128 + ((slot * 16) ^ ((row & 7) << 4))) = areg[q];
        }
#pragma unroll
        for (int q = 0; q < BQ; ++q) {
            int lin = q * 256 + tid;
            int row = lin >> 3, slot = lin & 7;
            *(uint4*)(Bs[buf] + row * 128 + ((slot * 16) ^ ((row & 7) << 4))) = breg[q];
        }
        __syncthreads();
        if (c < 1) { loadA(1); loadB(1); }
#pragma unroll
        for (int ks = 0; ks < 2; ++ks) {
            short8 a[4], b[NFRAG];
            int kb = ks * 64 + (lane >> 4) * 16;
#pragma unroll
            for (int m = 0; m < 4; ++m) {
                int row = wm * 64 + m * 16 + (lane & 15);
                a[m] = *(const short8*)(As[buf] + row * 128 + (kb ^ swz));
            }
#pragma unroll
            for (int n = 0; n < NFRAG; ++n) {
                int col = wn * (NC / 2) + n * 16 + (lane & 15);
                b[n] = *(const short8*)(Bs[buf] + col * 128 + (kb ^ swz));
            }
#pragma unroll
            for (int m = 0; m < 4; ++m)
#pragma unroll
                for (int n = 0; n < NFRAG; ++n)
                    acc[m][n] = __builtin_amdgcn_mfma_f32_16x16x32_bf16(a[m], b[n], acc[m][n], 0, 0, 0);
        }
        __syncthreads();
    }

    int colbase = wn * (NC / 2) + (lane & 15);
    float bias_v[NFRAG];
#pragma unroll
    for (int n = 0; n < NFRAG; ++n) bias_v[n] = bias[colbase + n * 16];
#pragma unroll
    for (int m = 0; m < 4; ++m) {
        int rl0 = m0 + wm * 64 + m * 16 + ((lane >> 4) << 2);
#pragma unroll
        for (int n = 0; n < NFRAG; ++n) {
            int col = colbase + n * 16;
#pragma unroll
            for (int q = 0; q < 4; ++q) {
                float v = fmaxf(acc[m][n][q] + bias_v[n], 0.f);
                int row = rl0 + q;
                if (F32OUT) {
                    if (row < M) ((float*)outp)[(size_t)row * NC + col] = v;
                } else {
                    float vo = __shfl_xor(v, 1);
                    if (((lane & 1) == 0) && row < M)
                        ((unsigned*)outp)[(size_t)row * (NC / 2) + (col >> 1)] = pack2(v, vo);
                }
            }
        }
    }
}

// ---------------- aggregation: t[nl][512] bf16 = sum_e wcomp[et,:] (x) h[src] ----------------

__global__ __launch_bounds__(256) void agg_kernel(const unsigned* __restrict__ hin, // [N][64] bf16x2
                                                  const int* __restrict__ offsets,
                                                  const int* __restrict__ packed,
                                                  const float* __restrict__ wcomp,  // [8][4]
                                                  unsigned* __restrict__ tbuf,      // [len][256]
                                                  int chunk_start, int chunk_len) {
    __shared__ float wc[32];
    int tid = threadIdx.x;
    if (tid < 32) wc[tid] = wcomp[tid];
    __syncthreads();
    int nl = blockIdx.x * 4 + (tid >> 6);
    int lane = tid & 63;
    if (nl >= chunk_len) return;
    int n = chunk_start + nl;
    int beg = offsets[n], end = offsets[n + 1];
    float a0x = 0.f, a0y = 0.f, a1x = 0.f, a1y = 0.f;
    float a2x = 0.f, a2y = 0.f, a3x = 0.f, a3y = 0.f;
    auto edge = [&](unsigned u, unsigned hv) {
        int r = (int)(u >> 20);
        float hx = __uint_as_float(hv << 16);
        float hy = __uint_as_float(hv & 0xffff0000u);
        float w0 = wc[r * 4 + 0], w1 = wc[r * 4 + 1];
        float w2 = wc[r * 4 + 2], w3 = wc[r * 4 + 3];
        a0x = fmaf(w0, hx, a0x); a0y = fmaf(w0, hy, a0y);
        a1x = fmaf(w1, hx, a1x); a1y = fmaf(w1, hy, a1y);
        a2x = fmaf(w2, hx, a2x); a2y = fmaf(w2, hy, a2y);
        a3x = fmaf(w3, hx, a3x); a3y = fmaf(w3, hy, a3y);
    };
    int e = beg;
    for (; e + 4 <= end; e += 4) {
        unsigned u0 = (unsigned)packed[e + 0];
        unsigned u1 = (unsigned)packed[e + 1];
        unsigned u2 = (unsigned)packed[e + 2];
        unsigned u3 = (unsigned)packed[e + 3];
        unsigned h0 = hin[(size_t)(u0 & 0xFFFFFu) * 64 + lane];
        unsigned h1 = hin[(size_t)(u1 & 0xFFFFFu) * 64 + lane];
        unsigned h2 = hin[(size_t)(u2 & 0xFFFFFu) * 64 + lane];
        unsigned h3 = hin[(size_t)(u3 & 0xFFFFFu) * 64 + lane];
        edge(u0, h0); edge(u1, h1); edge(u2, h2); edge(u3, h3);
    }
    for (; e < end; ++e) {
        unsigned u = (unsigned)packed[e];
        unsigned hv = hin[(size_t)(u & 0xFFFFFu) * 64 + lane];
        edge(u, hv);
    }
    size_t tb = (size_t)nl * 256 + lane;
    tbuf[tb + 0]   = pack2(a0x, a0y);
    tbuf[tb + 64]  = pack2(a1x, a1y);
    tbuf[tb + 128] = pack2(a2x, a2y);
    tbuf[tb + 192] = pack2(a3x, a3y);
}

// ---------------- conv GEMM (MFMA): hout = relu([t|h] @ BT^T + hbias), bf16 out ----------------

__global__ __launch_bounds__(256) void conv_gemm(const unsigned* __restrict__ tbuf, // [len][256]
                                                 const unsigned* __restrict__ hin,  // [N][64]
                                                 const unsigned short* __restrict__ BT, // [128][640]
                                                 const float* __restrict__ hbias,   // [128]
                                                 unsigned* __restrict__ hout,       // [N][64]
                                                 int chunk_start, int chunk_len) {
    __shared__ char As[2][16384];
    __shared__ char Bs[2][16384];
    int tid = threadIdx.x;
    int lane = tid & 63;
    int wave = tid >> 6;
    int wm = wave >> 1, wn = wave & 1;
    int m0 = blockIdx.x * 128;

    uint4 areg[4], breg[4];

    auto loadA = [&](int c) {
#pragma unroll
        for (int q = 0; q < 4; ++q) {
            int lin = q * 256 + tid;
            int row = lin >> 3, slot = lin & 7;
            int lr = m0 + row;
            lr = (lr < chunk_len) ? lr : (chunk_len - 1);
            const char* srcp;
            if (c < 8)
                srcp = (const char*)(tbuf + (size_t)lr * 256) + c * 128 + slot * 16;
            else
                srcp = (const char*)(hin + (size_t)(chunk_start + lr) * 64) + (c - 8) * 128 + slot * 16;
            areg[q] = *(const uint4*)srcp;
        }
    };
    auto loadB = [&](int c) {
#pragma unroll
        for (int q = 0; q < 4; ++q) {
            int lin = q * 256 + tid;
            int n = lin >> 3, slot = lin & 7;
            breg[q] = *(const uint4*)((const char*)(BT + (size_t)n * 640) + c * 128 + slot * 16);
        }
    };

    f32x4 acc[4][4];
#pragma unroll
    for (int m = 0; m < 4; ++m)
#pragma unroll
        for (int n = 0; n < 4; ++n) acc[m][n] = (f32x4)0.f;

    loadA(0); loadB(0);
    int swz = (lane & 7) << 4;

    for (int c = 0; c < 10; ++c) {
        int buf = c & 1;
#pragma unroll
        for (int q = 0; q < 4; ++q) {
            int lin = q * 256 + tid;
            int row = lin >> 3, slot = lin & 7;
            int off = row * 128 + ((slot * 16) ^ ((row & 7) << 4));
            *(uint4*)(As[buf] + off) = areg[q];
            *(uint4*)(Bs[buf] + off) = breg[q];
        }
        __syncthreads();
        if (c < 9) { loadA(c + 1); loadB(c + 1); }
#pragma unroll
        for (int ks = 0; ks < 2; ++ks) {
            short8 a[4], b[4];
            int kb = ks * 64 + (lane >> 4) * 16;
#pragma unroll
            for (int m = 0; m < 4; ++m) {
                int row = wm * 64 + m * 16 + (lane & 15);
                a[m] = *(const short8*)(As[buf] + row * 128 + (kb ^ swz));
            }
#pragma unroll
            for (int n = 0; n < 4; ++n) {
                int col = wn * 64 + n * 16 + (lane & 15);
                b[n] = *(const short8*)(Bs[buf] + col * 128 + (kb ^ swz));
            }
#pragma unroll
            for (int m = 0; m < 4; ++m)
#pragma unroll
                for (int n = 0; n < 4; ++n)
                    acc[m][n] = __builtin_amdgcn_mfma_f32_16x16x32_bf16(a[m], b[n], acc[m][n], 0, 0, 0);
        }
        __syncthreads();
    }

    int colbase = wn * 64 + (lane & 15);
    float bias_v[4];
#pragma unroll
    for (int n = 0; n < 4; ++n) bias_v[n] = hbias[colbase + n * 16];
#pragma unroll
    for (int m = 0; m < 4; ++m) {
        int rl0 = m0 + wm * 64 + m * 16 + ((lane >> 4) << 2);
#pragma unroll
        for (int n = 0; n < 4; ++n) {
            int col = colbase + n * 16;
#pragma unroll
            for (int q = 0; q < 4; ++q) {
                float v = fmaxf(acc[m][n][q] + bias_v[n], 0.f);
                float vo = __shfl_xor(v, 1);
                int lr = rl0 + q;
                if (((lane & 1) == 0) && lr < chunk_len) {
                    hout[(size_t)(chunk_start + lr) * 64 + (col >> 1)] = pack2(v, vo);
                }
            }
        }
    }
}

// ---------------- launch ----------------

static inline size_t align256(size_t x) { return (x + 255) & ~(size_t)255; }

extern "C" void kernel_launch(void* const* d_in, const int* in_sizes, int n_in,
                              void* d_out, int out_size, void* d_ws, size_t ws_size,
                              hipStream_t stream) {
    const float* feat   = (const float*)d_in[0];
    const float* win    = (const float*)d_in[1];
    const float* bin_   = (const float*)d_in[2];
    const float* basis0 = (const float*)d_in[3];
    const float* wcomp0 = (const float*)d_in[4];
    const float* loop0  = (const float*)d_in[5];
    const float* hbias0 = (const float*)d_in[6];
    const float* basis1 = (const float*)d_in[7];
    const float* wcomp1 = (const float*)d_in[8];
    const float* loop1  = (const float*)d_in[9];
    const float* hbias1 = (const float*)d_in[10];
    const float* wout   = (const float*)d_in[11];
    const float* bout   = (const float*)d_in[12];
    const int*   src    = (const int*)d_in[13];
    const int*   dst    = (const int*)d_in[14];
    const int*   etyp   = (const int*)d_in[15];
    float* outp = (float*)d_out;

    size_t off = 0;
    char* wsb = (char*)d_ws;
    auto walloc = [&](size_t bytes) { void* p = wsb + off; off += align256(bytes); return p; };
    unsigned* hA  = (unsigned*)walloc((size_t)NN * 64 * 4);     // 25.6 MB
    unsigned* hB  = (unsigned*)walloc((size_t)NN * 64 * 4);     // 25.6 MB
    int* offsets  = (int*)walloc((size_t)(NN + 1) * 4);
    int* counts   = (int*)walloc((size_t)NN * 4);
    int* totals   = (int*)walloc((size_t)NBLK * 4);
    int* gcursor  = (int*)walloc((size_t)NBUK * 4);
    int* packed   = (int*)walloc((size_t)EE * 4);               // 6.4 MB
    unsigned* tmp = (unsigned*)walloc((size_t)EE * 4);          // 6.4 MB
    unsigned short* BT0 = (unsigned short*)walloc((size_t)128 * 640 * 2);
    unsigned short* BT1 = (unsigned short*)walloc((size_t)128 * 640 * 2);
    unsigned short* winT = (unsigned short*)walloc((size_t)128 * 128 * 2);
    unsigned short* woutT = (unsigned short*)walloc((size_t)64 * 128 * 2);
    size_t fixed = off;

    int nchunk = 1;
    while (nchunk < 32) {
        size_t rows = (size_t)(NN + nchunk - 1) / nchunk;
        if (fixed + rows * 1024 <= ws_size) break;
        nchunk *= 2;
    }
    int chunk_rows = (NN + nchunk - 1) / nchunk;
    unsigned* tbuf = (unsigned*)(wsb + fixed);

    // CSR build: count -> scan -> bin (two-pass, write-local)
    hipMemsetAsync(counts, 0, (size_t)NN * 4, stream);
    count_kernel<<<(EE + 255) / 256, 256, 0, stream>>>(dst, counts);
    scan1<<<NBLK, 256, 0, stream>>>(counts, offsets, totals);
    scan2<<<1, 1, 0, stream>>>(totals, offsets);
    scan3<<<(NN + 255) / 256, 256, 0, stream>>>(offsets, totals);
    init_cursor<<<1, 128, 0, stream>>>(offsets, gcursor);
    bin_pass1<<<P1BLOCKS, 256, 0, stream>>>(src, dst, etyp, gcursor, tmp);
    bin_pass2<<<NBUK, 1024, 0, stream>>>(tmp, offsets, packed);

    // weight conversions (one launch)
    convert_weights<<<(188416 + 255) / 256, 256, 0, stream>>>(
        basis0, loop0, basis1, loop1, win, wout, BT0, BT1, winT, woutT);

    int gblocks = (NN + 127) / 128;  // 782
    // input layer (MFMA, A converted f32->bf16 in-kernel): hA = relu(feat @ winT^T + bin_)
    gemm128<128, false, true><<<gblocks, 256, 0, stream>>>(feat, winT, bin_, hA, NN);

    // conv layer 0: hA -> hB
    for (int s = 0; s < NN; s += chunk_rows) {
        int len = (NN - s < chunk_rows) ? (NN - s) : chunk_rows;
        agg_kernel<<<(len + 3) / 4, 256, 0, stream>>>(hA, offsets, packed, wcomp0, tbuf, s, len);
        conv_gemm<<<(len + 127) / 128, 256, 0, stream>>>(tbuf, hA, BT0, hbias0, hB, s, len);
    }
    // conv layer 1: hB -> hA
    for (int s = 0; s < NN; s += chunk_rows) {
        int len = (NN - s < chunk_rows) ? (NN - s) : chunk_rows;
        agg_kernel<<<(len + 3) / 4, 256, 0, stream>>>(hB, offsets, packed, wcomp1, tbuf, s, len);
        conv_gemm<<<(len + 127) / 128, 256, 0, stream>>>(tbuf, hB, BT1, hbias1, hA, s, len);
    }
    // output layer (MFMA): out = relu(hA @ woutT^T + bout), f32
    gemm128<64, true, false><<<gblocks, 256, 0, stream>>>(hA, woutT, bout, outp, NN);
}